// Round 5
// baseline (1517.239 us; speedup 1.0000x reference)
//
#include <hip/hip_runtime.h>
#include <hip/hip_bf16.h>
#include <math.h>
#include <stdint.h>

#define EPS_BN 1e-5f

constexpr int Bx = 8;
constexpr int Nx = 8192;
constexpr int NP = 1024;

typedef __attribute__((ext_vector_type(8))) __bf16 bf16x8;
typedef __attribute__((ext_vector_type(4))) float  f32x4;
typedef __attribute__((ext_vector_type(2))) float  f32x2;
typedef unsigned int uint32;
typedef unsigned long long u64;

// ---- DPP wave64 reduction helpers (row_shr 1/2/4/8 + row_bcast 15/31 -> lane 63) ----
template<int CTRL, int RMASK>
__device__ __forceinline__ float dpp_max_f32(float v) {
    int t = __builtin_amdgcn_update_dpp(__float_as_int(v), __float_as_int(v), CTRL, RMASK, 0xf, false);
    return fmaxf(v, __int_as_float(t));
}
__device__ __forceinline__ float wave_max_f32(float v) {
    v = dpp_max_f32<0x111, 0xf>(v);   // row_shr:1
    v = dpp_max_f32<0x112, 0xf>(v);   // row_shr:2
    v = dpp_max_f32<0x114, 0xf>(v);   // row_shr:4
    v = dpp_max_f32<0x118, 0xf>(v);   // row_shr:8
    v = dpp_max_f32<0x142, 0xa>(v);   // row_bcast:15 -> rows 1,3
    v = dpp_max_f32<0x143, 0xc>(v);   // row_bcast:31 -> rows 2,3
    return __int_as_float(__builtin_amdgcn_readlane(__float_as_int(v), 63));
}
template<int CTRL, int RMASK>
__device__ __forceinline__ int dpp_min_i32(int v) {
    int t = __builtin_amdgcn_update_dpp(v, v, CTRL, RMASK, 0xf, false);
    return min(v, t);
}
__device__ __forceinline__ int wave_min_i32(int v) {
    v = dpp_min_i32<0x111, 0xf>(v);
    v = dpp_min_i32<0x112, 0xf>(v);
    v = dpp_min_i32<0x114, 0xf>(v);
    v = dpp_min_i32<0x118, 0xf>(v);
    v = dpp_min_i32<0x142, 0xa>(v);
    v = dpp_min_i32<0x143, 0xc>(v);
    return __builtin_amdgcn_readlane(v, 63);
}
template<int CTRL, int RMASK>
__device__ __forceinline__ int dpp_sum_i32(int c) {
    int t = __builtin_amdgcn_update_dpp(0, c, CTRL, RMASK, 0xf, true);  // OOB -> 0
    return c + t;
}
__device__ __forceinline__ int wave_sum_i32(int c) {
    c = dpp_sum_i32<0x111, 0xf>(c);
    c = dpp_sum_i32<0x112, 0xf>(c);
    c = dpp_sum_i32<0x114, 0xf>(c);
    c = dpp_sum_i32<0x118, 0xf>(c);
    c = dpp_sum_i32<0x142, 0xa>(c);
    c = dpp_sum_i32<0x143, 0xc>(c);
    return __builtin_amdgcn_readlane(c, 63);
}

// ---------------- K0: preprocess weights (bf16 W, bn scale/mean/bias) ----------------
__global__ __launch_bounds__(256) void prep_kernel(
    const float* __restrict__ w1, const float* __restrict__ w2,
    const float* g1, const float* b1, const float* m1, const float* v1,
    const float* g2, const float* b2, const float* m2, const float* v2,
    __bf16* __restrict__ W1bf, __bf16* __restrict__ W2bf, float* __restrict__ lsb)
{
    int t = blockIdx.x * 256 + threadIdx.x;
    if (t < 16384)      W1bf[t] = (__bf16)w1[t];
    else if (t < 32768) W2bf[t - 16384] = (__bf16)w2[t - 16384];
    if (t < 128) {
        lsb[t]       = g1[t] * (1.0f / sqrtf(v1[t] + EPS_BN));
        lsb[128 + t] = m1[t];
        lsb[256 + t] = b1[t];
        lsb[384 + t] = g2[t] * (1.0f / sqrtf(v2[t] + EPS_BN));
        lsb[512 + t] = m2[t];
        lsb[640 + t] = b2[t];
    }
}

// ---------------- K1: per-point embed MLP (3->64->64) + pts4=(x,y,z,n2) ----------------
__global__ __launch_bounds__(256) void embed_kernel(
    const float* __restrict__ x,
    const float* __restrict__ w1, const float* __restrict__ w2,
    const float* g1, const float* b1, const float* m1, const float* v1,
    const float* g2, const float* b2, const float* m2, const float* v2,
    float* __restrict__ f, float4* __restrict__ pts4)
{
    __shared__ float  W1L[192];
    __shared__ float4 W2L[1024];   // W2[o][e] rows, as float4
    __shared__ float  s1L[64], m1L[64], b1L[64], s2L[64], m2L[64], b2L[64];
    int tid = threadIdx.x;
    if (tid < 192) W1L[tid] = w1[tid];
    for (int i = tid; i < 1024; i += 256) W2L[i] = ((const float4*)w2)[i];
    if (tid < 64) {
        s1L[tid] = g1[tid] * (1.0f / sqrtf(v1[tid] + EPS_BN));
        m1L[tid] = m1[tid];  b1L[tid] = b1[tid];
        s2L[tid] = g2[tid] * (1.0f / sqrtf(v2[tid] + EPS_BN));
        m2L[tid] = m2[tid];  b2L[tid] = b2[tid];
    }
    __syncthreads();
    int n = blockIdx.x * 256 + tid;      // 0..65535 (b*N+n)
    const float* xp = x + (size_t)n * 3;
    float x0 = xp[0], x1 = xp[1], x2 = xp[2];
    {
#pragma clang fp contract(off)
        float nv = (x0 * x0 + x1 * x1) + x2 * x2;   // matches np sum order exactly
        pts4[n] = make_float4(x0, x1, x2, nv);
    }
    float t[64];
#pragma unroll
    for (int e = 0; e < 64; e++) {
        float v = fmaf(x2, W1L[e*3+2], fmaf(x1, W1L[e*3+1], x0 * W1L[e*3]));
        v = (v - m1L[e]) * s1L[e] + b1L[e];
        t[e] = fmaxf(v, 0.0f);
    }
    float acc[64];
#pragma unroll
    for (int o = 0; o < 64; o++) acc[o] = 0.0f;
#pragma unroll
    for (int e4 = 0; e4 < 16; e4++) {
        float a0 = t[e4*4], a1 = t[e4*4+1], a2 = t[e4*4+2], a3 = t[e4*4+3];
#pragma unroll
        for (int o = 0; o < 64; o++) {
            float4 w = W2L[o*16 + e4];
            acc[o] = fmaf(a3, w.w, fmaf(a2, w.z, fmaf(a1, w.y, fmaf(a0, w.x, acc[o]))));
        }
    }
    float4* fo = (float4*)(f + (size_t)n * 64);
#pragma unroll
    for (int q = 0; q < 16; q++) {
        float r0 = fmaxf((acc[q*4+0] - m2L[q*4+0]) * s2L[q*4+0] + b2L[q*4+0], 0.f);
        float r1 = fmaxf((acc[q*4+1] - m2L[q*4+1]) * s2L[q*4+1] + b2L[q*4+1], 0.f);
        float r2 = fmaxf((acc[q*4+2] - m2L[q*4+2]) * s2L[q*4+2] + b2L[q*4+2], 0.f);
        float r3 = fmaxf((acc[q*4+3] - m2L[q*4+3]) * s2L[q*4+3] + b2L[q*4+3], 0.f);
        fo[q] = make_float4(r0, r1, r2, r3);
    }
}

// ---------------- K2: farthest point sampling (1 block / batch, 512 thr, LDS-resident) ----
// VALU-issue-bound on 8 CUs: keep the dist update packed (v_pk_*_f32), reduce the
// argmax value first (cheap f32 DPP), resolve the index lazily (scan only on the
// matching wave), then one barrier + 8-partial u64 combine.
__global__ __launch_bounds__(512) void fps_kernel(
    const float* __restrict__ x, int* __restrict__ fpsI,
    float* __restrict__ out0, float* __restrict__ out2)
{
#pragma clang fp contract(off)
    __shared__ float4 xyzL[Nx];        // 128 KB: all points of this batch
    __shared__ u64 redK[2][8];
    int b = blockIdx.x, tid = threadIdx.x;
    int wid = tid >> 6, lane = tid & 63;
    const float* xb = x + (size_t)b * Nx * 3;
    f32x2 px[8], py[8], pz[8], dist[8];    // 16 pts/thread: pair i = pts (16t+2i, 16t+2i+1)
    {
        const float4* xv = (const float4*)(xb + tid * 48);  // 48 floats = 16 pts
        float F[48];
#pragma unroll
        for (int q = 0; q < 12; q++) {
            float4 v = xv[q];
            F[q*4+0]=v.x; F[q*4+1]=v.y; F[q*4+2]=v.z; F[q*4+3]=v.w;
        }
#pragma unroll
        for (int i = 0; i < 8; i++) {
            px[i] = (f32x2){F[(2*i)*3+0], F[(2*i+1)*3+0]};
            py[i] = (f32x2){F[(2*i)*3+1], F[(2*i+1)*3+1]};
            pz[i] = (f32x2){F[(2*i)*3+2], F[(2*i+1)*3+2]};
            dist[i] = (f32x2){1e10f, 1e10f};
        }
#pragma unroll
        for (int j = 0; j < 16; j++) {     // staggered: conflict-free LDS writes
            int jj = (j + (tid & 15)) & 15;
            xyzL[tid*16 + jj] = make_float4(F[jj*3], F[jj*3+1], F[jj*3+2], 0.f);
        }
    }
    __syncthreads();
    int far = 0;
    for (int s = 0; s < NP; s++) {
        float4 c = xyzL[far];                   // ds_read_b128 broadcast
        if (tid == 0) {
            fpsI[b*NP + s] = far;
            int o = (b*NP + s) * 3;
            out0[o]=c.x; out0[o+1]=c.y; out0[o+2]=c.z;
            out2[o]=c.x; out2[o+1]=c.y; out2[o+2]=c.z;
        }
        f32x2 cx = {c.x, c.x}, cy = {c.y, c.y}, cz = {c.z, c.z};
        f32x2 mx2 = {-1.0f, -1.0f};
#pragma unroll
        for (int i = 0; i < 8; i++) {
            f32x2 dx = px[i] - cx, dy = py[i] - cy, dz = pz[i] - cz;
            f32x2 sq = (dx*dx + dy*dy) + dz*dz;    // per-lane IEEE, exact np order
            f32x2 dm = __builtin_elementwise_min(dist[i], sq);   // v_pk_min_f32
            dist[i] = dm;
            mx2 = __builtin_elementwise_max(mx2, dm);            // v_pk_max_f32
        }
        float bv = fmaxf(mx2.x, mx2.y);
        float wv = wave_max_f32(bv);            // cheap f32 DPP (2 inst/level)
        int bi = 0x7fffffff;
        if (bv == wv) {                         // usually 1 lane of 1 wave
#pragma unroll
            for (int i = 7; i >= 0; i--) {      // high->low so lowest idx wins
                if (dist[i].y == wv) bi = tid*16 + 2*i + 1;
                if (dist[i].x == wv) bi = tid*16 + 2*i;
            }
        }
        int wbi = wave_min_i32(bi);
        if (lane == 0)
            redK[s & 1][wid] = ((u64)__float_as_uint(wv) << 32) | (uint32)(~wbi);
        __syncthreads();
        u64 mx = redK[s & 1][0];
#pragma unroll
        for (int i = 1; i < 8; i++) {
            u64 t = redK[s & 1][i];
            if (t > mx) mx = t;
        }
        far = (int)(~(uint32)mx);
    }
}

// ---------------- K3: KNN top-32 via register radix-select, 1 block / query ----------------
__global__ __launch_bounds__(256, 4) void knn_select_kernel(
    const float4* __restrict__ pts4, const int* __restrict__ fpsI, int* __restrict__ knn)
{
#pragma clang fp contract(off)
    __shared__ int redC[2][4];
    __shared__ int redM[4];
    __shared__ int cntL;
    int tid = threadIdx.x;
    int wid = tid >> 6, lane = tid & 63;
    int bs = blockIdx.x;           // b*1024 + s
    int b = bs >> 10;
    const float4* P = pts4 + (size_t)b * Nx;
    int c = fpsI[bs];
    float4 q = P[c];
    if (tid == 0) cntL = 0;
    uint32 key[32];
#pragma unroll
    for (int i = 0; i < 32; i++) {
        int n = tid + i * 256;
        float4 p = P[n];
        float dot = (q.x * p.x + q.y * p.y) + q.z * p.z;   // exact reference order
        float d = (q.w + p.w) - 2.0f * dot;
        uint32 u = __float_as_uint(d);
        key[i] = (u & 0x80000000u) ? ~u : (u | 0x80000000u);  // monotonic uint transform
    }
    // find T = key of 32nd smallest; krem = #elements equal to T still needed
    uint32 prefix = 0;
    int krem = 32;
    for (int bit = 31; bit >= 0; bit--) {
        uint32 s = prefix >> bit;       // target high-bits with current bit = 0
        int cnt = 0;
#pragma unroll
        for (int i = 0; i < 32; i++)
            cnt += ((key[i] >> bit) == s) ? 1 : 0;
        cnt = wave_sum_i32(cnt);        // DPP, no LDS
        if (lane == 0) redC[bit & 1][wid] = cnt;
        __syncthreads();                // single barrier per pass (double-buffered)
        int total = redC[bit & 1][0] + redC[bit & 1][1] + redC[bit & 1][2] + redC[bit & 1][3];
        if (total < krem) { prefix |= (1u << bit); krem -= total; }
    }
    // emit: all keys < T (order-free), then krem ties with smallest indices
    int* row = knn + (size_t)bs * 32;
#pragma unroll
    for (int i = 0; i < 32; i++) {
        if (key[i] < prefix) {
            int pos = atomicAdd(&cntL, 1);
            row[pos] = tid + i * 256;
        }
    }
    __syncthreads();
    int last = -1;
    for (int t = 0; t < krem; t++) {
        int local = 0x7fffffff;
#pragma unroll
        for (int i = 0; i < 32; i++) {
            int n = tid + i * 256;
            if (key[i] == prefix && n > last && n < local) local = n;
        }
        local = min(local, __shfl_xor(local, 1));  local = min(local, __shfl_xor(local, 2));
        local = min(local, __shfl_xor(local, 4));  local = min(local, __shfl_xor(local, 8));
        local = min(local, __shfl_xor(local, 16)); local = min(local, __shfl_xor(local, 32));
        if (lane == 0) redM[wid] = local;
        __syncthreads();
        int g = min(min(redM[0], redM[1]), min(redM[2], redM[3]));
        if (tid == 0) row[32 - krem + t] = g;
        last = g;
        __syncthreads();
    }
}

// ---------------- K4: gather + 2x (32x128 @ 128x128) MFMA + bn/relu + k-max ----------------
__global__ __launch_bounds__(128) void group_conv_kernel(
    const float* __restrict__ f, const int* __restrict__ fpsI, const int* __restrict__ knn,
    const __bf16* __restrict__ W1bf, const __bf16* __restrict__ W2bf,
    const float* __restrict__ lsb,
    float* __restrict__ out1, float* __restrict__ out3)
{
    constexpr int LDW = 136;   // +8 bf16 pad -> 2-way max LDS conflict
    __shared__ __bf16 featL[32 * LDW];
    __shared__ __bf16 h1L[32 * LDW];
    __shared__ float  cf[64];
    __shared__ int    nb[32];
    int bs = blockIdx.x;
    int b = bs >> 10, s = bs & 1023;
    int tid = threadIdx.x;
    int w = tid >> 6, lane = tid & 63;
    int l15 = lane & 15, quad = lane >> 4;
    int nbase = w * 64;
    const f32x4 vzero = {0.f, 0.f, 0.f, 0.f};

    // B-frags for layer 1 (issued early, no LDS dependency). W1 is (o,j) == Bt layout.
    bf16x8 bf1[4][4];
#pragma unroll
    for (int nt = 0; nt < 4; nt++)
#pragma unroll
        for (int kt = 0; kt < 4; kt++)
            bf1[nt][kt] = *(const bf16x8*)(W1bf + (size_t)(nbase + nt*16 + l15) * 128 + kt*32 + quad*8);

    if (tid < 32) nb[tid] = knn[(size_t)bs * 32 + tid];
    int cIdx = fpsI[bs];
    if (tid < 16) {
        float4 v = *(const float4*)(f + ((size_t)b * Nx + cIdx) * 64 + tid * 4);
        cf[tid*4]=v.x; cf[tid*4+1]=v.y; cf[tid*4+2]=v.z; cf[tid*4+3]=v.w;
    }
    __syncthreads();
    {   // build feat = [f_nb - f_c | f_c] in bf16
        int k = tid >> 2, j0 = (tid & 3) * 16;
        const float* fr = f + ((size_t)b * Nx + nb[k]) * 64 + j0;
#pragma unroll
        for (int jj = 0; jj < 16; jj += 4) {
            float4 v = *(const float4*)(fr + jj);
            float c0=cf[j0+jj], c1=cf[j0+jj+1], c2=cf[j0+jj+2], c3=cf[j0+jj+3];
            __bf16* dl = featL + k * LDW + j0 + jj;
            dl[0]=(__bf16)(v.x-c0); dl[1]=(__bf16)(v.y-c1); dl[2]=(__bf16)(v.z-c2); dl[3]=(__bf16)(v.w-c3);
            __bf16* dr = dl + 64;
            dr[0]=(__bf16)c0; dr[1]=(__bf16)c1; dr[2]=(__bf16)c2; dr[3]=(__bf16)c3;
        }
    }
    __syncthreads();

    f32x4 acc[2][4];
#pragma unroll
    for (int mt = 0; mt < 2; mt++)
#pragma unroll
        for (int nt = 0; nt < 4; nt++) acc[mt][nt] = vzero;
#pragma unroll
    for (int mt = 0; mt < 2; mt++)
#pragma unroll
        for (int kt = 0; kt < 4; kt++) {
            bf16x8 a = *(const bf16x8*)(featL + (mt*16 + l15) * LDW + kt*32 + quad*8);
#pragma unroll
            for (int nt = 0; nt < 4; nt++)
                acc[mt][nt] = __builtin_amdgcn_mfma_f32_16x16x32_bf16(a, bf1[nt][kt], acc[mt][nt], 0, 0, 0);
        }

    // prefetch layer-2 B-frags while epilogue 1 runs
    bf16x8 bf2[4][4];
#pragma unroll
    for (int nt = 0; nt < 4; nt++)
#pragma unroll
        for (int kt = 0; kt < 4; kt++)
            bf2[nt][kt] = *(const bf16x8*)(W2bf + (size_t)(nbase + nt*16 + l15) * 128 + kt*32 + quad*8);

#pragma unroll
    for (int nt = 0; nt < 4; nt++) {
        int o = nbase + nt*16 + l15;
        float sc = lsb[o], mm = lsb[128+o], bb = lsb[256+o];
#pragma unroll
        for (int mt = 0; mt < 2; mt++)
#pragma unroll
            for (int rj = 0; rj < 4; rj++) {
                float h = fmaxf((acc[mt][nt][rj] - mm) * sc + bb, 0.0f);
                h1L[(mt*16 + quad*4 + rj) * LDW + o] = (__bf16)h;   // C/D: row=quad*4+reg, col=l15
            }
    }
    __syncthreads();

#pragma unroll
    for (int mt = 0; mt < 2; mt++)
#pragma unroll
        for (int nt = 0; nt < 4; nt++) acc[mt][nt] = vzero;
#pragma unroll
    for (int mt = 0; mt < 2; mt++)
#pragma unroll
        for (int kt = 0; kt < 4; kt++) {
            bf16x8 a = *(const bf16x8*)(h1L + (mt*16 + l15) * LDW + kt*32 + quad*8);
#pragma unroll
            for (int nt = 0; nt < 4; nt++)
                acc[mt][nt] = __builtin_amdgcn_mfma_f32_16x16x32_bf16(a, bf2[nt][kt], acc[mt][nt], 0, 0, 0);
        }

#pragma unroll
    for (int nt = 0; nt < 4; nt++) {
        int o = nbase + nt*16 + l15;
        float sc = lsb[384+o], mm = lsb[512+o], bb = lsb[640+o];
        float vmx = 0.0f;   // relu => all values >= 0, so 0-init is exact
#pragma unroll
        for (int mt = 0; mt < 2; mt++)
#pragma unroll
            for (int rj = 0; rj < 4; rj++) {
                float h = fmaxf((acc[mt][nt][rj] - mm) * sc + bb, 0.0f);
                vmx = fmaxf(vmx, h);
            }
        vmx = fmaxf(vmx, __shfl_xor(vmx, 16));
        vmx = fmaxf(vmx, __shfl_xor(vmx, 32));
        if (quad == 0) {
            size_t off = (size_t)b * (128*1024) + (size_t)o * 1024 + s;
            out1[off] = vmx;
            out3[off] = vmx;
        }
    }
}

extern "C" void kernel_launch(void* const* d_in, const int* in_sizes, int n_in,
                              void* d_out, int out_size, void* d_ws, size_t ws_size,
                              hipStream_t stream)
{
    const float* x    = (const float*)d_in[0];
    const float* c1w  = (const float*)d_in[1];
    const float* c2w  = (const float*)d_in[2];
    const float* l1w  = (const float*)d_in[3];
    const float* l2w  = (const float*)d_in[4];
    const float* bn1g = (const float*)d_in[5];
    const float* bn1b = (const float*)d_in[6];
    const float* bn1m = (const float*)d_in[7];
    const float* bn1v = (const float*)d_in[8];
    const float* bn2g = (const float*)d_in[9];
    const float* bn2b = (const float*)d_in[10];
    const float* bn2m = (const float*)d_in[11];
    const float* bn2v = (const float*)d_in[12];
    const float* lb1g = (const float*)d_in[13];
    const float* lb1b = (const float*)d_in[14];
    const float* lb1m = (const float*)d_in[15];
    const float* lb1v = (const float*)d_in[16];
    const float* lb2g = (const float*)d_in[17];
    const float* lb2b = (const float*)d_in[18];
    const float* lb2m = (const float*)d_in[19];
    const float* lb2v = (const float*)d_in[20];

    float* out = (float*)d_out;
    char* ws = (char*)d_ws;
    float*  f    = (float*)(ws);                 // 8*8192*64 f32   = 16,777,216 B
    float4* pts4 = (float4*)(ws + 16777216);     // 8*8192 float4   =  1,048,576 B
    int*    fpsI = (int*)   (ws + 17825792);     // 8*1024 i32      =     32,768 B
    int*    knn  = (int*)   (ws + 17858560);     // 8*1024*32 i32   =  1,048,576 B
    __bf16* W1bf = (__bf16*)(ws + 18907136);     // 16384 bf16      =     32,768 B
    __bf16* W2bf = (__bf16*)(ws + 18939904);     // 16384 bf16      =     32,768 B
    float*  lsb  = (float*) (ws + 18972672);     // 768 f32         =      3,072 B

    float* out0 = out;              // new_xyz      (8,1024,3)
    float* out1 = out + 24576;      // feature_0    (8,128,1024)
    float* out2 = out + 1073152;    // new_xyz copy
    float* out3 = out + 1097728;    // feature_0 copy

    prep_kernel<<<128, 256, 0, stream>>>(l1w, l2w,
        lb1g, lb1b, lb1m, lb1v, lb2g, lb2b, lb2m, lb2v, W1bf, W2bf, lsb);
    embed_kernel<<<256, 256, 0, stream>>>(x, c1w, c2w,
        bn1g, bn1b, bn1m, bn1v, bn2g, bn2b, bn2m, bn2v, f, pts4);
    fps_kernel<<<8, 512, 0, stream>>>(x, fpsI, out0, out2);
    knn_select_kernel<<<8192, 256, 0, stream>>>(pts4, fpsI, knn);
    group_conv_kernel<<<8192, 128, 0, stream>>>(f, fpsI, knn, W1bf, W2bf, lsb, out1, out3);
}

// Round 6
// 1132.668 us; speedup vs baseline: 1.3395x; 1.3395x over previous
//
#include <hip/hip_runtime.h>
#include <hip/hip_bf16.h>
#include <math.h>
#include <stdint.h>

#define EPS_BN 1e-5f

constexpr int Nx = 8192;
constexpr int NP = 1024;
constexpr int NWORK = 248;   // worker blocks (grid 256 = 8 fps + 248 workers)

typedef __attribute__((ext_vector_type(8))) __bf16 bf16x8;
typedef __attribute__((ext_vector_type(4))) float  f32x4;
typedef __attribute__((ext_vector_type(2))) float  f32x2;
typedef unsigned int uint32;
typedef unsigned long long u64;

// ---- DPP wave64 reduction helpers (row_shr 1/2/4/8 + row_bcast 15/31 -> lane 63) ----
template<int CTRL, int RMASK>
__device__ __forceinline__ u64 dpp_max_u64(u64 k) {
    uint32 klo = (uint32)k, khi = (uint32)(k >> 32);
    uint32 plo = (uint32)__builtin_amdgcn_update_dpp((int)klo, (int)klo, CTRL, RMASK, 0xf, false);
    uint32 phi = (uint32)__builtin_amdgcn_update_dpp((int)khi, (int)khi, CTRL, RMASK, 0xf, false);
    u64 p = ((u64)phi << 32) | plo;
    return (p > k) ? p : k;
}
__device__ __forceinline__ u64 wave_max_u64(u64 k) {
    k = dpp_max_u64<0x111, 0xf>(k);
    k = dpp_max_u64<0x112, 0xf>(k);
    k = dpp_max_u64<0x114, 0xf>(k);
    k = dpp_max_u64<0x118, 0xf>(k);
    k = dpp_max_u64<0x142, 0xa>(k);
    k = dpp_max_u64<0x143, 0xc>(k);
    uint32 rlo = (uint32)__builtin_amdgcn_readlane((int)(uint32)k, 63);
    uint32 rhi = (uint32)__builtin_amdgcn_readlane((int)(k >> 32), 63);
    return ((u64)rhi << 32) | rlo;
}
template<int CTRL, int RMASK>
__device__ __forceinline__ int dpp_sum_i32(int c) {
    int t = __builtin_amdgcn_update_dpp(0, c, CTRL, RMASK, 0xf, true);  // OOB -> 0
    return c + t;
}
__device__ __forceinline__ int wave_sum_i32(int c) {
    c = dpp_sum_i32<0x111, 0xf>(c);
    c = dpp_sum_i32<0x112, 0xf>(c);
    c = dpp_sum_i32<0x114, 0xf>(c);
    c = dpp_sum_i32<0x118, 0xf>(c);
    c = dpp_sum_i32<0x142, 0xa>(c);
    c = dpp_sum_i32<0x143, 0xc>(c);
    return __builtin_amdgcn_readlane(c, 63);
}
template<int CTRL, int RMASK>
__device__ __forceinline__ int dpp_min_i32(int v) {
    int t = __builtin_amdgcn_update_dpp(v, v, CTRL, RMASK, 0xf, false);
    return min(v, t);
}
__device__ __forceinline__ int wave_min_i32(int v) {
    v = dpp_min_i32<0x111, 0xf>(v);
    v = dpp_min_i32<0x112, 0xf>(v);
    v = dpp_min_i32<0x114, 0xf>(v);
    v = dpp_min_i32<0x118, 0xf>(v);
    v = dpp_min_i32<0x142, 0xa>(v);
    v = dpp_min_i32<0x143, 0xc>(v);
    return __builtin_amdgcn_readlane(v, 63);
}

// ---------------- K1: embed MLP (3->64->64) + pts4 ; block 256 = weight prep ----------------
__global__ __launch_bounds__(256) void embed_prep_kernel(
    const float* __restrict__ x,
    const float* __restrict__ w1, const float* __restrict__ w2,
    const float* g1, const float* b1, const float* m1, const float* v1,
    const float* g2, const float* b2, const float* m2, const float* v2,
    const float* __restrict__ lw1, const float* __restrict__ lw2,
    const float* lg1, const float* lb1, const float* lm1, const float* lv1,
    const float* lg2, const float* lb2, const float* lm2, const float* lv2,
    float* __restrict__ f, float4* __restrict__ pts4,
    __bf16* __restrict__ W1bf, __bf16* __restrict__ W2bf, float* __restrict__ lsb)
{
    int tid = threadIdx.x;
    if (blockIdx.x == 256) {     // prep role
        for (int t = tid; t < 16384; t += 256) {
            W1bf[t] = (__bf16)lw1[t];
            W2bf[t] = (__bf16)lw2[t];
        }
        if (tid < 128) {
            lsb[tid]       = lg1[tid] * (1.0f / sqrtf(lv1[tid] + EPS_BN));
            lsb[128 + tid] = lm1[tid];
            lsb[256 + tid] = lb1[tid];
            lsb[384 + tid] = lg2[tid] * (1.0f / sqrtf(lv2[tid] + EPS_BN));
            lsb[512 + tid] = lm2[tid];
            lsb[640 + tid] = lb2[tid];
        }
        return;
    }
    __shared__ float  W1L[192];
    __shared__ float4 W2L[1024];
    __shared__ float  s1L[64], m1L[64], b1L[64], s2L[64], m2L[64], b2L[64];
    if (tid < 192) W1L[tid] = w1[tid];
    for (int i = tid; i < 1024; i += 256) W2L[i] = ((const float4*)w2)[i];
    if (tid < 64) {
        s1L[tid] = g1[tid] * (1.0f / sqrtf(v1[tid] + EPS_BN));
        m1L[tid] = m1[tid];  b1L[tid] = b1[tid];
        s2L[tid] = g2[tid] * (1.0f / sqrtf(v2[tid] + EPS_BN));
        m2L[tid] = m2[tid];  b2L[tid] = b2[tid];
    }
    __syncthreads();
    int n = blockIdx.x * 256 + tid;
    const float* xp = x + (size_t)n * 3;
    float x0 = xp[0], x1 = xp[1], x2 = xp[2];
    {
#pragma clang fp contract(off)
        float nv = (x0 * x0 + x1 * x1) + x2 * x2;   // exact np sum order
        pts4[n] = make_float4(x0, x1, x2, nv);
    }
    float t[64];
#pragma unroll
    for (int e = 0; e < 64; e++) {
        float v = fmaf(x2, W1L[e*3+2], fmaf(x1, W1L[e*3+1], x0 * W1L[e*3]));
        v = (v - m1L[e]) * s1L[e] + b1L[e];
        t[e] = fmaxf(v, 0.0f);
    }
    float acc[64];
#pragma unroll
    for (int o = 0; o < 64; o++) acc[o] = 0.0f;
#pragma unroll
    for (int e4 = 0; e4 < 16; e4++) {
        float a0 = t[e4*4], a1 = t[e4*4+1], a2 = t[e4*4+2], a3 = t[e4*4+3];
#pragma unroll
        for (int o = 0; o < 64; o++) {
            float4 w = W2L[o*16 + e4];
            acc[o] = fmaf(a3, w.w, fmaf(a2, w.z, fmaf(a1, w.y, fmaf(a0, w.x, acc[o]))));
        }
    }
    float4* fo = (float4*)(f + (size_t)n * 64);
#pragma unroll
    for (int q = 0; q < 16; q++) {
        float r0 = fmaxf((acc[q*4+0] - m2L[q*4+0]) * s2L[q*4+0] + b2L[q*4+0], 0.f);
        float r1 = fmaxf((acc[q*4+1] - m2L[q*4+1]) * s2L[q*4+1] + b2L[q*4+1], 0.f);
        float r2 = fmaxf((acc[q*4+2] - m2L[q*4+2]) * s2L[q*4+2] + b2L[q*4+2], 0.f);
        float r3 = fmaxf((acc[q*4+3] - m2L[q*4+3]) * s2L[q*4+3] + b2L[q*4+3], 0.f);
        fo[q] = make_float4(r0, r1, r2, r3);
    }
}

// ---------------- Fused: blocks 0..7 = FPS producer, blocks 8..255 = KNN+conv workers ----
// fpsI element doubles as the ready flag: poison 0xAA.. is negative; fps publishes the
// index itself with a relaxed agent-scope atomic store (no fence, no vmcnt drain).
__global__ __launch_bounds__(512, 1) void fused_kernel(
    const float* __restrict__ x, const float4* __restrict__ pts4,
    const float* __restrict__ f, int* fpsI,
    const __bf16* __restrict__ W1bf, const __bf16* __restrict__ W2bf,
    const float* __restrict__ lsb,
    float* __restrict__ out0, float* __restrict__ out1,
    float* __restrict__ out2, float* __restrict__ out3)
{
    __shared__ __attribute__((aligned(16))) char smemRaw[131200];
    int tid = threadIdx.x;

    if (blockIdx.x < 8) {
        // ================= FPS role (round-4 proven body) =================
#pragma clang fp contract(off)
        float4* xyzL = (float4*)smemRaw;                 // 128 KB
        u64*    redK = (u64*)(smemRaw + 131072);         // [2][8]
        int b = blockIdx.x;
        int wid = tid >> 6, lane = tid & 63;
        const float* xb = x + (size_t)b * Nx * 3;
        f32x2 px[8], py[8], pz[8], dist[8];
        {
            const float4* xv = (const float4*)(xb + tid * 48);
            float F[48];
#pragma unroll
            for (int q = 0; q < 12; q++) {
                float4 v = xv[q];
                F[q*4+0]=v.x; F[q*4+1]=v.y; F[q*4+2]=v.z; F[q*4+3]=v.w;
            }
#pragma unroll
            for (int i = 0; i < 8; i++) {
                px[i] = (f32x2){F[(2*i)*3+0], F[(2*i+1)*3+0]};
                py[i] = (f32x2){F[(2*i)*3+1], F[(2*i+1)*3+1]};
                pz[i] = (f32x2){F[(2*i)*3+2], F[(2*i+1)*3+2]};
                dist[i] = (f32x2){1e10f, 1e10f};
            }
#pragma unroll
            for (int j = 0; j < 16; j++) {
                int jj = (j + (tid & 15)) & 15;
                xyzL[tid*16 + jj] = make_float4(F[jj*3], F[jj*3+1], F[jj*3+2], 0.f);
            }
        }
        __syncthreads();
        int far = 0;
        for (int st = 0; st < NP; st++) {
            float4 c = xyzL[far];
            if (tid == 0) {
                __hip_atomic_store(&fpsI[b*NP + st], far, __ATOMIC_RELAXED, __HIP_MEMORY_SCOPE_AGENT);
                int o = (b*NP + st) * 3;
                out0[o]=c.x; out0[o+1]=c.y; out0[o+2]=c.z;
                out2[o]=c.x; out2[o+1]=c.y; out2[o+2]=c.z;
            }
            f32x2 cx = {c.x, c.x}, cy = {c.y, c.y}, cz = {c.z, c.z};
            f32x2 bv2 = {-1.0f, -1.0f};
#pragma unroll
            for (int i = 0; i < 8; i++) {
                f32x2 dx = px[i] - cx, dy = py[i] - cy, dz = pz[i] - cz;
                f32x2 sq = (dx*dx + dy*dy) + dz*dz;    // per-lane IEEE, exact np order
                f32x2 dm;
                dm.x = fminf(dist[i].x, sq.x); dm.y = fminf(dist[i].y, sq.y);
                dist[i] = dm;
                bv2.x = fmaxf(bv2.x, dm.x); bv2.y = fmaxf(bv2.y, dm.y);
            }
            float bv = fmaxf(bv2.x, bv2.y);
            int bi = 0;
#pragma unroll
            for (int i = 7; i >= 0; i--) {          // high->low so lowest idx wins
                if (dist[i].y == bv) bi = tid*16 + 2*i + 1;
                if (dist[i].x == bv) bi = tid*16 + 2*i;
            }
            u64 bk = ((u64)__float_as_uint(bv) << 32) | (uint32)(~bi);
            bk = wave_max_u64(bk);
            if (lane == 0) redK[(st & 1)*8 + wid] = bk;
            __syncthreads();
            u64 mx = redK[(st & 1)*8 + 0];
#pragma unroll
            for (int i = 1; i < 8; i++) {
                u64 t2 = redK[(st & 1)*8 + i];
                if (t2 > mx) mx = t2;
            }
            far = (int)(~(uint32)mx);
        }
        return;
    }

    // ================= Worker role: per query, radix-select KNN then MFMA conv =========
    __bf16* featL = (__bf16*)smemRaw;                 // 32*136*2 = 8704 B
    __bf16* h1L   = (__bf16*)(smemRaw + 8704);        // 8704 B
    float*  cf    = (float*) (smemRaw + 17408);       // 256 B
    int*    rowL  = (int*)   (smemRaw + 17664);       // 128 B
    int*    redC  = (int*)   (smemRaw + 17792);       // [2][8]
    int*    redM  = (int*)   (smemRaw + 17856);       // [2][8]
    int*    misc  = (int*)   (smemRaw + 17920);       // [0]=cnt [1]=idx

    int wv = tid >> 6, lane = tid & 63;
    int l15 = lane & 15, quad = lane >> 4;
    int nbase = wv * 16;
    const f32x4 vzero = {0.f, 0.f, 0.f, 0.f};

    // per-wave weight fragments / bn params (constant across queries)
    bf16x8 bf1[4], bf2[4];
#pragma unroll
    for (int kt = 0; kt < 4; kt++) {
        bf1[kt] = *(const bf16x8*)(W1bf + (size_t)(nbase + l15) * 128 + kt*32 + quad*8);
        bf2[kt] = *(const bf16x8*)(W2bf + (size_t)(nbase + l15) * 128 + kt*32 + quad*8);
    }
    int oc = nbase + l15;
    float sc1 = lsb[oc],     mm1 = lsb[128+oc], bb1 = lsb[256+oc];
    float sc2 = lsb[384+oc], mm2 = lsb[512+oc], bb2 = lsb[640+oc];

    for (int t = (int)blockIdx.x - 8; t < 8192; t += NWORK) {
        int b = t & 7, s = t >> 3;          // s-major: workers trail fps monotonically
        int q = (b << 10) | s;
        if (tid == 0) {
            int v;
            while ((v = __hip_atomic_load(&fpsI[q], __ATOMIC_RELAXED, __HIP_MEMORY_SCOPE_AGENT)) < 0)
                __builtin_amdgcn_s_sleep(2);
            misc[1] = v;
            misc[0] = 0;
        }
        __syncthreads();
        int cIdx = misc[1];
        if (tid < 16) {      // center features -> cf (consumed after many barriers)
            float4 v = *(const float4*)(f + ((size_t)b * Nx + cIdx) * 64 + tid * 4);
            cf[tid*4]=v.x; cf[tid*4+1]=v.y; cf[tid*4+2]=v.z; cf[tid*4+3]=v.w;
        }
        // ---- KNN radix-select (512 thr, 16 keys each) ----
        uint32 key[16];
        {
#pragma clang fp contract(off)
            const float4* P = pts4 + (size_t)b * Nx;
            float4 qp = P[cIdx];
#pragma unroll
            for (int i = 0; i < 16; i++) {
                int n = tid + (i << 9);
                float4 p = P[n];
                float dot = (qp.x * p.x + qp.y * p.y) + qp.z * p.z;   // exact ref order
                float d = (qp.w + p.w) - 2.0f * dot;
                uint32 u = __float_as_uint(d);
                key[i] = (u & 0x80000000u) ? ~u : (u | 0x80000000u);
            }
        }
        uint32 prefix = 0; int krem = 32;
        for (int bit = 31; bit >= 0; bit--) {
            uint32 sv = prefix >> bit;
            int cnt = 0;
#pragma unroll
            for (int i = 0; i < 16; i++)
                cnt += ((key[i] >> bit) == sv) ? 1 : 0;
            cnt = wave_sum_i32(cnt);
            if (lane == 0) redC[(bit & 1)*8 + wv] = cnt;
            __syncthreads();
            int total = 0;
#pragma unroll
            for (int j = 0; j < 8; j++) total += redC[(bit & 1)*8 + j];
            if (total < krem) { prefix |= (1u << bit); krem -= total; }
        }
#pragma unroll
        for (int i = 0; i < 16; i++) {
            if (key[i] < prefix) {
                int pos = atomicAdd(&misc[0], 1);
                rowL[pos] = tid + (i << 9);
            }
        }
        __syncthreads();
        int last = -1;
        for (int tt = 0; tt < krem; tt++) {    // krem is block-uniform
            int local = 0x7fffffff;
#pragma unroll
            for (int i = 0; i < 16; i++) {
                int n = tid + (i << 9);
                if (key[i] == prefix && n > last && n < local) local = n;
            }
            local = wave_min_i32(local);
            if (lane == 0) redM[(tt & 1)*8 + wv] = local;
            __syncthreads();
            int g = 0x7fffffff;
#pragma unroll
            for (int j = 0; j < 8; j++) g = min(g, redM[(tt & 1)*8 + j]);
            if (tid == 0) rowL[32 - krem + tt] = g;
            last = g;
        }
        __syncthreads();                        // rowL final
        // ---- build feat = [f_nb - f_c | f_c] in bf16 ----
        {
            int k = tid >> 4, j0 = (tid & 15) * 4;
            int nbr = rowL[k];
            float4 v = *(const float4*)(f + ((size_t)b * Nx + nbr) * 64 + j0);
            float c0 = cf[j0], c1 = cf[j0+1], c2 = cf[j0+2], c3 = cf[j0+3];
            __bf16* dl = featL + k * 136 + j0;
            dl[0]=(__bf16)(v.x-c0); dl[1]=(__bf16)(v.y-c1); dl[2]=(__bf16)(v.z-c2); dl[3]=(__bf16)(v.w-c3);
            __bf16* dr = dl + 64;
            dr[0]=(__bf16)c0; dr[1]=(__bf16)c1; dr[2]=(__bf16)c2; dr[3]=(__bf16)c3;
        }
        __syncthreads();
        // ---- layer 1: (32x128)@(128x16 per wave) ----
        f32x4 acc[2];
        acc[0] = vzero; acc[1] = vzero;
#pragma unroll
        for (int mt = 0; mt < 2; mt++)
#pragma unroll
            for (int kt = 0; kt < 4; kt++) {
                bf16x8 a = *(const bf16x8*)(featL + (mt*16 + l15) * 136 + kt*32 + quad*8);
                acc[mt] = __builtin_amdgcn_mfma_f32_16x16x32_bf16(a, bf1[kt], acc[mt], 0, 0, 0);
            }
#pragma unroll
        for (int mt = 0; mt < 2; mt++)
#pragma unroll
            for (int rj = 0; rj < 4; rj++) {
                float h = fmaxf((acc[mt][rj] - mm1) * sc1 + bb1, 0.0f);
                h1L[(mt*16 + quad*4 + rj) * 136 + oc] = (__bf16)h;
            }
        __syncthreads();
        // ---- layer 2 + k-max ----
        acc[0] = vzero; acc[1] = vzero;
#pragma unroll
        for (int mt = 0; mt < 2; mt++)
#pragma unroll
            for (int kt = 0; kt < 4; kt++) {
                bf16x8 a = *(const bf16x8*)(h1L + (mt*16 + l15) * 136 + kt*32 + quad*8);
                acc[mt] = __builtin_amdgcn_mfma_f32_16x16x32_bf16(a, bf2[kt], acc[mt], 0, 0, 0);
            }
        float vmx = 0.0f;                       // relu => >= 0
#pragma unroll
        for (int mt = 0; mt < 2; mt++)
#pragma unroll
            for (int rj = 0; rj < 4; rj++) {
                float h = fmaxf((acc[mt][rj] - mm2) * sc2 + bb2, 0.0f);
                vmx = fmaxf(vmx, h);
            }
        vmx = fmaxf(vmx, __shfl_xor(vmx, 16));
        vmx = fmaxf(vmx, __shfl_xor(vmx, 32));
        if (quad == 0) {
            size_t off = (size_t)b * (128*1024) + (size_t)oc * 1024 + s;
            out1[off] = vmx;
            out3[off] = vmx;
        }
        __syncthreads();                        // LDS reuse next query
    }
}

extern "C" void kernel_launch(void* const* d_in, const int* in_sizes, int n_in,
                              void* d_out, int out_size, void* d_ws, size_t ws_size,
                              hipStream_t stream)
{
    const float* x    = (const float*)d_in[0];
    const float* c1w  = (const float*)d_in[1];
    const float* c2w  = (const float*)d_in[2];
    const float* l1w  = (const float*)d_in[3];
    const float* l2w  = (const float*)d_in[4];
    const float* bn1g = (const float*)d_in[5];
    const float* bn1b = (const float*)d_in[6];
    const float* bn1m = (const float*)d_in[7];
    const float* bn1v = (const float*)d_in[8];
    const float* bn2g = (const float*)d_in[9];
    const float* bn2b = (const float*)d_in[10];
    const float* bn2m = (const float*)d_in[11];
    const float* bn2v = (const float*)d_in[12];
    const float* lb1g = (const float*)d_in[13];
    const float* lb1b = (const float*)d_in[14];
    const float* lb1m = (const float*)d_in[15];
    const float* lb1v = (const float*)d_in[16];
    const float* lb2g = (const float*)d_in[17];
    const float* lb2b = (const float*)d_in[18];
    const float* lb2m = (const float*)d_in[19];
    const float* lb2v = (const float*)d_in[20];

    float* out = (float*)d_out;
    char* ws = (char*)d_ws;
    float*  f    = (float*)(ws);                 // 8*8192*64 f32   = 16,777,216 B
    float4* pts4 = (float4*)(ws + 16777216);     // 8*8192 float4   =  1,048,576 B
    int*    fpsI = (int*)   (ws + 17825792);     // 8*1024 i32 (poison 0xAA = not-ready flag)
    __bf16* W1bf = (__bf16*)(ws + 17858560);     // 16384 bf16
    __bf16* W2bf = (__bf16*)(ws + 17891328);     // 16384 bf16
    float*  lsb  = (float*) (ws + 17924096);     // 768 f32

    float* out0 = out;              // new_xyz      (8,1024,3)
    float* out1 = out + 24576;      // feature_0    (8,128,1024)
    float* out2 = out + 1073152;    // new_xyz copy
    float* out3 = out + 1097728;    // feature_0 copy

    embed_prep_kernel<<<257, 256, 0, stream>>>(x, c1w, c2w,
        bn1g, bn1b, bn1m, bn1v, bn2g, bn2b, bn2m, bn2v,
        l1w, l2w, lb1g, lb1b, lb1m, lb1v, lb2g, lb2b, lb2m, lb2v,
        f, pts4, W1bf, W2bf, lsb);
    fused_kernel<<<256, 512, 0, stream>>>(x, pts4, f, fpsI, W1bf, W2bf, lsb,
        out0, out1, out2, out3);
}

// Round 7
// 1102.260 us; speedup vs baseline: 1.3765x; 1.0276x over previous
//
#include <hip/hip_runtime.h>
#include <hip/hip_bf16.h>
#include <math.h>
#include <stdint.h>

#define EPS_BN 1e-5f

constexpr int Nx = 8192;
constexpr int NP = 1024;
constexpr int NWORK = 248;   // worker blocks (grid 256 = 8 fps + 248 workers)
constexpr int NEMB  = 128;   // worker blocks 8..135 also embed a 512-pt slice
#define POISON_I ((int)0xAAAAAAAA)

typedef __attribute__((ext_vector_type(8))) __bf16 bf16x8;
typedef __attribute__((ext_vector_type(4))) float  f32x4;
typedef __attribute__((ext_vector_type(2))) float  f32x2;
typedef unsigned int uint32;
typedef unsigned long long u64;

// ---- DPP wave64 reduction helpers (row_shr 1/2/4/8 + row_bcast 15/31 -> lane 63) ----
template<int CTRL, int RMASK>
__device__ __forceinline__ u64 dpp_max_u64(u64 k) {
    uint32 klo = (uint32)k, khi = (uint32)(k >> 32);
    uint32 plo = (uint32)__builtin_amdgcn_update_dpp((int)klo, (int)klo, CTRL, RMASK, 0xf, false);
    uint32 phi = (uint32)__builtin_amdgcn_update_dpp((int)khi, (int)khi, CTRL, RMASK, 0xf, false);
    u64 p = ((u64)phi << 32) | plo;
    return (p > k) ? p : k;
}
__device__ __forceinline__ u64 wave_max_u64(u64 k) {
    k = dpp_max_u64<0x111, 0xf>(k);
    k = dpp_max_u64<0x112, 0xf>(k);
    k = dpp_max_u64<0x114, 0xf>(k);
    k = dpp_max_u64<0x118, 0xf>(k);
    k = dpp_max_u64<0x142, 0xa>(k);
    k = dpp_max_u64<0x143, 0xc>(k);
    uint32 rlo = (uint32)__builtin_amdgcn_readlane((int)(uint32)k, 63);
    uint32 rhi = (uint32)__builtin_amdgcn_readlane((int)(k >> 32), 63);
    return ((u64)rhi << 32) | rlo;
}
template<int CTRL, int RMASK>
__device__ __forceinline__ int dpp_sum_i32(int c) {
    int t = __builtin_amdgcn_update_dpp(0, c, CTRL, RMASK, 0xf, true);  // OOB -> 0
    return c + t;
}
__device__ __forceinline__ int wave_sum_i32(int c) {
    c = dpp_sum_i32<0x111, 0xf>(c);
    c = dpp_sum_i32<0x112, 0xf>(c);
    c = dpp_sum_i32<0x114, 0xf>(c);
    c = dpp_sum_i32<0x118, 0xf>(c);
    c = dpp_sum_i32<0x142, 0xa>(c);
    c = dpp_sum_i32<0x143, 0xc>(c);
    return __builtin_amdgcn_readlane(c, 63);
}
template<int CTRL, int RMASK>
__device__ __forceinline__ int dpp_min_i32(int v) {
    int t = __builtin_amdgcn_update_dpp(v, v, CTRL, RMASK, 0xf, false);
    return min(v, t);
}
__device__ __forceinline__ int wave_min_i32(int v) {
    v = dpp_min_i32<0x111, 0xf>(v);
    v = dpp_min_i32<0x112, 0xf>(v);
    v = dpp_min_i32<0x114, 0xf>(v);
    v = dpp_min_i32<0x118, 0xf>(v);
    v = dpp_min_i32<0x142, 0xa>(v);
    v = dpp_min_i32<0x143, 0xc>(v);
    return __builtin_amdgcn_readlane(v, 63);
}

// =================== THE single kernel: fps | embed+worker roles ===================
__global__ __launch_bounds__(512, 1) void mega_kernel(
    const float* __restrict__ x,
    const float* __restrict__ w1, const float* __restrict__ w2,
    const float* g1, const float* b1, const float* m1, const float* v1,
    const float* g2, const float* b2, const float* m2, const float* v2,
    const float* __restrict__ lw1, const float* __restrict__ lw2,
    const float* lg1, const float* lb1, const float* lm1, const float* lv1,
    const float* lg2, const float* lb2, const float* lm2, const float* lv2,
    float* __restrict__ f, float4* __restrict__ pts4, int* fpsI, int* done,
    float* __restrict__ out0, float* __restrict__ out1,
    float* __restrict__ out2, float* __restrict__ out3)
{
    __shared__ __attribute__((aligned(16))) char smemRaw[131200];
    int tid = threadIdx.x;

    if (blockIdx.x < 8) {
        // ================= FPS role (round-4 proven body + packed min/max) ==========
#pragma clang fp contract(off)
        float4* xyzL = (float4*)smemRaw;                 // 128 KB
        u64*    redK = (u64*)(smemRaw + 131072);         // [2][8]
        int b = blockIdx.x;
        int wid = tid >> 6, lane = tid & 63;
        const float* xb = x + (size_t)b * Nx * 3;
        f32x2 px[8], py[8], pz[8], dist[8];
        {
            const float4* xv = (const float4*)(xb + tid * 48);
            float F[48];
#pragma unroll
            for (int q = 0; q < 12; q++) {
                float4 v = xv[q];
                F[q*4+0]=v.x; F[q*4+1]=v.y; F[q*4+2]=v.z; F[q*4+3]=v.w;
            }
#pragma unroll
            for (int i = 0; i < 8; i++) {
                px[i] = (f32x2){F[(2*i)*3+0], F[(2*i+1)*3+0]};
                py[i] = (f32x2){F[(2*i)*3+1], F[(2*i+1)*3+1]};
                pz[i] = (f32x2){F[(2*i)*3+2], F[(2*i+1)*3+2]};
                dist[i] = (f32x2){1e10f, 1e10f};
            }
#pragma unroll
            for (int j = 0; j < 16; j++) {
                int jj = (j + (tid & 15)) & 15;
                xyzL[tid*16 + jj] = make_float4(F[jj*3], F[jj*3+1], F[jj*3+2], 0.f);
            }
        }
        __syncthreads();
        int far = 0;
        for (int st = 0; st < NP; st++) {
            float4 c = xyzL[far];
            if (tid == 0) {
                __hip_atomic_store(&fpsI[b*NP + st], far, __ATOMIC_RELAXED, __HIP_MEMORY_SCOPE_AGENT);
                int o = (b*NP + st) * 3;
                out0[o]=c.x; out0[o+1]=c.y; out0[o+2]=c.z;
                out2[o]=c.x; out2[o+1]=c.y; out2[o+2]=c.z;
            }
            f32x2 cx = {c.x, c.x}, cy = {c.y, c.y}, cz = {c.z, c.z};
            f32x2 bv2 = {-1.0f, -1.0f};
#pragma unroll
            for (int i = 0; i < 8; i++) {
                f32x2 dx = px[i] - cx, dy = py[i] - cy, dz = pz[i] - cz;
                f32x2 sq = (dx*dx + dy*dy) + dz*dz;    // per-lane IEEE, exact np order
                f32x2 dm = __builtin_elementwise_min(dist[i], sq);
                dist[i] = dm;
                bv2 = __builtin_elementwise_max(bv2, dm);
            }
            float bv = fmaxf(bv2.x, bv2.y);
            int bi = 0;
#pragma unroll
            for (int i = 7; i >= 0; i--) {          // high->low so lowest idx wins
                if (dist[i].y == bv) bi = tid*16 + 2*i + 1;
                if (dist[i].x == bv) bi = tid*16 + 2*i;
            }
            u64 bk = ((u64)__float_as_uint(bv) << 32) | (uint32)(~bi);
            bk = wave_max_u64(bk);
            if (lane == 0) redK[(st & 1)*8 + wid] = bk;
            __syncthreads();
            u64 mx = redK[(st & 1)*8 + 0];
#pragma unroll
            for (int i = 1; i < 8; i++) {
                u64 t2 = redK[(st & 1)*8 + i];
                if (t2 > mx) mx = t2;
            }
            far = (int)(~(uint32)mx);
        }
        return;
    }

    // ================= Worker role ====================================================
    int wb = (int)blockIdx.x - 8;

    if (wb < NEMB) {
        // ---- embed a 512-point slice: f + pts4 (LDS overlay, released by sync below) --
        float*  W1L = (float*)smemRaw;                    // 192 f  @0
        float4* W2L = (float4*)(smemRaw + 1024);          // 1024 float4
        float*  s1L = (float*)(smemRaw + 17408);
        float*  m1L = (float*)(smemRaw + 17664);
        float*  b1L = (float*)(smemRaw + 17920);
        float*  s2L = (float*)(smemRaw + 18176);
        float*  m2L = (float*)(smemRaw + 18432);
        float*  b2L = (float*)(smemRaw + 18688);
        if (tid < 192) W1L[tid] = w1[tid];
        for (int i = tid; i < 1024; i += 512) W2L[i] = ((const float4*)w2)[i];
        if (tid < 64) {
            s1L[tid] = g1[tid] * (1.0f / sqrtf(v1[tid] + EPS_BN));
            m1L[tid] = m1[tid];  b1L[tid] = b1[tid];
            s2L[tid] = g2[tid] * (1.0f / sqrtf(v2[tid] + EPS_BN));
            m2L[tid] = m2[tid];  b2L[tid] = b2[tid];
        }
        __syncthreads();
        int n = wb * 512 + tid;                 // 0..65535
        const float* xp = x + (size_t)n * 3;
        float x0 = xp[0], x1 = xp[1], x2 = xp[2];
        {
#pragma clang fp contract(off)
            float nv = (x0 * x0 + x1 * x1) + x2 * x2;   // exact np sum order
            pts4[n] = make_float4(x0, x1, x2, nv);
        }
        float t[64];
#pragma unroll
        for (int e = 0; e < 64; e++) {
            float v = fmaf(x2, W1L[e*3+2], fmaf(x1, W1L[e*3+1], x0 * W1L[e*3]));
            v = (v - m1L[e]) * s1L[e] + b1L[e];
            t[e] = fmaxf(v, 0.0f);
        }
        float acc[64];
#pragma unroll
        for (int o = 0; o < 64; o++) acc[o] = 0.0f;
#pragma unroll
        for (int e4 = 0; e4 < 16; e4++) {
            float a0 = t[e4*4], a1 = t[e4*4+1], a2 = t[e4*4+2], a3 = t[e4*4+3];
#pragma unroll
            for (int o = 0; o < 64; o++) {
                float4 w = W2L[o*16 + e4];
                acc[o] = fmaf(a3, w.w, fmaf(a2, w.z, fmaf(a1, w.y, fmaf(a0, w.x, acc[o]))));
            }
        }
        float4* fo = (float4*)(f + (size_t)n * 64);
#pragma unroll
        for (int q = 0; q < 16; q++) {
            float r0 = fmaxf((acc[q*4+0] - m2L[q*4+0]) * s2L[q*4+0] + b2L[q*4+0], 0.f);
            float r1 = fmaxf((acc[q*4+1] - m2L[q*4+1]) * s2L[q*4+1] + b2L[q*4+1], 0.f);
            float r2 = fmaxf((acc[q*4+2] - m2L[q*4+2]) * s2L[q*4+2] + b2L[q*4+2], 0.f);
            float r3 = fmaxf((acc[q*4+3] - m2L[q*4+3]) * s2L[q*4+3] + b2L[q*4+3], 0.f);
            fo[q] = make_float4(r0, r1, r2, r3);
        }
        __syncthreads();      // LDS free for query phase
        if (tid == 0)
            __hip_atomic_fetch_add(done, 1, __ATOMIC_RELEASE, __HIP_MEMORY_SCOPE_AGENT);
    }

    // ---- query-phase LDS overlay ----
    __bf16* featL = (__bf16*)smemRaw;                 // 8704 B
    __bf16* h1L   = (__bf16*)(smemRaw + 8704);        // 8704 B
    float*  cf    = (float*) (smemRaw + 17408);       // 256 B
    int*    rowL  = (int*)   (smemRaw + 17664);       // 128 B
    int*    redC  = (int*)   (smemRaw + 17792);       // [2][8]
    int*    redM  = (int*)   (smemRaw + 17856);       // [2][8]
    int*    misc  = (int*)   (smemRaw + 17920);       // [0]=cnt [1]=idx

    int wv = tid >> 6, lane = tid & 63;
    int l15 = lane & 15, quad = lane >> 4;
    int nbase = wv * 16;
    const f32x4 vzero = {0.f, 0.f, 0.f, 0.f};

    // per-wave weight fragments / bn params, straight from f32 inputs (no prep kernel)
    bf16x8 bf1[4], bf2[4];
#pragma unroll
    for (int kt = 0; kt < 4; kt++) {
        const float* p1 = lw1 + (size_t)(nbase + l15) * 128 + kt*32 + quad*8;
        const float* p2 = lw2 + (size_t)(nbase + l15) * 128 + kt*32 + quad*8;
        bf16x8 a1, a2;
#pragma unroll
        for (int j = 0; j < 8; j++) { a1[j] = (__bf16)p1[j]; a2[j] = (__bf16)p2[j]; }
        bf1[kt] = a1; bf2[kt] = a2;
    }
    int oc = nbase + l15;
    float sc1 = lg1[oc] * (1.0f / sqrtf(lv1[oc] + EPS_BN));
    float mm1 = lm1[oc], bb1 = lb1[oc];
    float sc2 = lg2[oc] * (1.0f / sqrtf(lv2[oc] + EPS_BN));
    float mm2 = lm2[oc], bb2 = lb2[oc];

    // wait for embed completion (cross-XCD: acquire fence before reading f/pts4)
    if (tid == 0) {
        while (__hip_atomic_load(done, __ATOMIC_RELAXED, __HIP_MEMORY_SCOPE_AGENT) != POISON_I + NEMB)
            __builtin_amdgcn_s_sleep(8);
    }
    __syncthreads();
    __threadfence();

    for (int t = wb; t < 8192; t += NWORK) {
        int b = t & 7, s = t >> 3;          // s-major: workers trail fps monotonically
        int q = (b << 10) | s;
        if (tid == 0) {
            int v;
            while ((v = __hip_atomic_load(&fpsI[q], __ATOMIC_RELAXED, __HIP_MEMORY_SCOPE_AGENT)) < 0)
                __builtin_amdgcn_s_sleep(2);
            misc[1] = v;
            misc[0] = 0;
        }
        __syncthreads();
        int cIdx = misc[1];
        if (tid < 16) {      // center features -> cf (consumed after many barriers)
            float4 v = *(const float4*)(f + ((size_t)b * Nx + cIdx) * 64 + tid * 4);
            cf[tid*4]=v.x; cf[tid*4+1]=v.y; cf[tid*4+2]=v.z; cf[tid*4+3]=v.w;
        }
        // ---- KNN radix-select (512 thr, 16 keys each) ----
        uint32 key[16];
        {
#pragma clang fp contract(off)
            const float4* P = pts4 + (size_t)b * Nx;
            float4 qp = P[cIdx];
#pragma unroll
            for (int i = 0; i < 16; i++) {
                int n = tid + (i << 9);
                float4 p = P[n];
                float dot = (qp.x * p.x + qp.y * p.y) + qp.z * p.z;   // exact ref order
                float d = (qp.w + p.w) - 2.0f * dot;
                uint32 u = __float_as_uint(d);
                key[i] = (u & 0x80000000u) ? ~u : (u | 0x80000000u);
            }
        }
        uint32 prefix = 0; int krem = 32;
        for (int bit = 31; bit >= 0; bit--) {
            uint32 sv = prefix >> bit;
            int cnt = 0;
#pragma unroll
            for (int i = 0; i < 16; i++)
                cnt += ((key[i] >> bit) == sv) ? 1 : 0;
            cnt = wave_sum_i32(cnt);
            if (lane == 0) redC[(bit & 1)*8 + wv] = cnt;
            __syncthreads();
            int total = 0;
#pragma unroll
            for (int j = 0; j < 8; j++) total += redC[(bit & 1)*8 + j];
            if (total < krem) { prefix |= (1u << bit); krem -= total; }
        }
#pragma unroll
        for (int i = 0; i < 16; i++) {
            if (key[i] < prefix) {
                int pos = atomicAdd(&misc[0], 1);
                rowL[pos] = tid + (i << 9);
            }
        }
        __syncthreads();
        int last = -1;
        for (int tt = 0; tt < krem; tt++) {    // krem is block-uniform
            int local = 0x7fffffff;
#pragma unroll
            for (int i = 0; i < 16; i++) {
                int n = tid + (i << 9);
                if (key[i] == prefix && n > last && n < local) local = n;
            }
            local = wave_min_i32(local);
            if (lane == 0) redM[(tt & 1)*8 + wv] = local;
            __syncthreads();
            int g = 0x7fffffff;
#pragma unroll
            for (int j = 0; j < 8; j++) g = min(g, redM[(tt & 1)*8 + j]);
            if (tid == 0) rowL[32 - krem + tt] = g;
            last = g;
        }
        __syncthreads();                        // rowL final
        // ---- build feat = [f_nb - f_c | f_c] in bf16 ----
        {
            int k = tid >> 4, j0 = (tid & 15) * 4;
            int nbr = rowL[k];
            float4 v = *(const float4*)(f + ((size_t)b * Nx + nbr) * 64 + j0);
            float c0 = cf[j0], c1 = cf[j0+1], c2 = cf[j0+2], c3 = cf[j0+3];
            __bf16* dl = featL + k * 136 + j0;
            dl[0]=(__bf16)(v.x-c0); dl[1]=(__bf16)(v.y-c1); dl[2]=(__bf16)(v.z-c2); dl[3]=(__bf16)(v.w-c3);
            __bf16* dr = dl + 64;
            dr[0]=(__bf16)c0; dr[1]=(__bf16)c1; dr[2]=(__bf16)c2; dr[3]=(__bf16)c3;
        }
        __syncthreads();
        // ---- layer 1: (32x128)@(128x16 per wave) ----
        f32x4 acc[2];
        acc[0] = vzero; acc[1] = vzero;
#pragma unroll
        for (int mt = 0; mt < 2; mt++)
#pragma unroll
            for (int kt = 0; kt < 4; kt++) {
                bf16x8 a = *(const bf16x8*)(featL + (mt*16 + l15) * 136 + kt*32 + quad*8);
                acc[mt] = __builtin_amdgcn_mfma_f32_16x16x32_bf16(a, bf1[kt], acc[mt], 0, 0, 0);
            }
#pragma unroll
        for (int mt = 0; mt < 2; mt++)
#pragma unroll
            for (int rj = 0; rj < 4; rj++) {
                float h = fmaxf((acc[mt][rj] - mm1) * sc1 + bb1, 0.0f);
                h1L[(mt*16 + quad*4 + rj) * 136 + oc] = (__bf16)h;
            }
        __syncthreads();
        // ---- layer 2 + k-max ----
        acc[0] = vzero; acc[1] = vzero;
#pragma unroll
        for (int mt = 0; mt < 2; mt++)
#pragma unroll
            for (int kt = 0; kt < 4; kt++) {
                bf16x8 a = *(const bf16x8*)(h1L + (mt*16 + l15) * 136 + kt*32 + quad*8);
                acc[mt] = __builtin_amdgcn_mfma_f32_16x16x32_bf16(a, bf2[kt], acc[mt], 0, 0, 0);
            }
        float vmx = 0.0f;                       // relu => >= 0
#pragma unroll
        for (int mt = 0; mt < 2; mt++)
#pragma unroll
            for (int rj = 0; rj < 4; rj++) {
                float h = fmaxf((acc[mt][rj] - mm2) * sc2 + bb2, 0.0f);
                vmx = fmaxf(vmx, h);
            }
        vmx = fmaxf(vmx, __shfl_xor(vmx, 16));
        vmx = fmaxf(vmx, __shfl_xor(vmx, 32));
        if (quad == 0) {
            size_t off = (size_t)b * (128*1024) + (size_t)oc * 1024 + s;
            out1[off] = vmx;
            out3[off] = vmx;
        }
        __syncthreads();                        // LDS reuse next query
    }
}

extern "C" void kernel_launch(void* const* d_in, const int* in_sizes, int n_in,
                              void* d_out, int out_size, void* d_ws, size_t ws_size,
                              hipStream_t stream)
{
    const float* x    = (const float*)d_in[0];
    const float* c1w  = (const float*)d_in[1];
    const float* c2w  = (const float*)d_in[2];
    const float* l1w  = (const float*)d_in[3];
    const float* l2w  = (const float*)d_in[4];
    const float* bn1g = (const float*)d_in[5];
    const float* bn1b = (const float*)d_in[6];
    const float* bn1m = (const float*)d_in[7];
    const float* bn1v = (const float*)d_in[8];
    const float* bn2g = (const float*)d_in[9];
    const float* bn2b = (const float*)d_in[10];
    const float* bn2m = (const float*)d_in[11];
    const float* bn2v = (const float*)d_in[12];
    const float* lb1g = (const float*)d_in[13];
    const float* lb1b = (const float*)d_in[14];
    const float* lb1m = (const float*)d_in[15];
    const float* lb1v = (const float*)d_in[16];
    const float* lb2g = (const float*)d_in[17];
    const float* lb2b = (const float*)d_in[18];
    const float* lb2m = (const float*)d_in[19];
    const float* lb2v = (const float*)d_in[20];

    float* out = (float*)d_out;
    char* ws = (char*)d_ws;
    float*  f    = (float*)(ws);                 // 8*8192*64 f32   = 16,777,216 B
    float4* pts4 = (float4*)(ws + 16777216);     // 8*8192 float4   =  1,048,576 B
    int*    fpsI = (int*)   (ws + 17825792);     // 8*1024 i32 (poison 0xAA = not-ready)
    int*    done = (int*)   (ws + 17858560);     // poison-base counter

    float* out0 = out;              // new_xyz      (8,1024,3)
    float* out1 = out + 24576;      // feature_0    (8,128,1024)
    float* out2 = out + 1073152;    // new_xyz copy
    float* out3 = out + 1097728;    // feature_0 copy

    mega_kernel<<<256, 512, 0, stream>>>(x, c1w, c2w,
        bn1g, bn1b, bn1m, bn1v, bn2g, bn2b, bn2m, bn2v,
        l1w, l2w, lb1g, lb1b, lb1m, lb1v, lb2g, lb2b, lb2m, lb2v,
        f, pts4, fpsI, done, out0, out1, out2, out3);
}

// Round 8
// 1042.828 us; speedup vs baseline: 1.4549x; 1.0570x over previous
//
#include <hip/hip_runtime.h>
#include <hip/hip_bf16.h>
#include <math.h>
#include <stdint.h>

#define EPS_BN 1e-5f

constexpr int Nx = 8192;
constexpr int NP = 1024;
constexpr int NWORK = 248;   // worker blocks (grid 256 = 8 fps + 248 workers)
constexpr int NEMB  = 128;   // worker blocks 8..135 also embed a 512-pt slice
#define POISON_I ((int)0xAAAAAAAA)

typedef __attribute__((ext_vector_type(8))) __bf16 bf16x8;
typedef __attribute__((ext_vector_type(4))) float  f32x4;
typedef __attribute__((ext_vector_type(2))) float  f32x2;
typedef unsigned int uint32;
typedef unsigned long long u64;

// ---- DPP wave64 reduction helpers ----
template<int CTRL, int RMASK>
__device__ __forceinline__ u64 dpp_max_u64(u64 k) {
    uint32 klo = (uint32)k, khi = (uint32)(k >> 32);
    uint32 plo = (uint32)__builtin_amdgcn_update_dpp((int)klo, (int)klo, CTRL, RMASK, 0xf, false);
    uint32 phi = (uint32)__builtin_amdgcn_update_dpp((int)khi, (int)khi, CTRL, RMASK, 0xf, false);
    u64 p = ((u64)phi << 32) | plo;
    return (p > k) ? p : k;
}
template<int CTRL, int RMASK>
__device__ __forceinline__ float dpp_max_f32(float v) {
    int t = __builtin_amdgcn_update_dpp(__float_as_int(v), __float_as_int(v), CTRL, RMASK, 0xf, false);
    return fmaxf(v, __int_as_float(t));
}
__device__ __forceinline__ float wave_max_f32(float v) {
    v = dpp_max_f32<0x111, 0xf>(v);   // row_shr:1
    v = dpp_max_f32<0x112, 0xf>(v);   // row_shr:2
    v = dpp_max_f32<0x114, 0xf>(v);   // row_shr:4
    v = dpp_max_f32<0x118, 0xf>(v);   // row_shr:8
    v = dpp_max_f32<0x142, 0xa>(v);   // row_bcast:15 -> rows 1,3
    v = dpp_max_f32<0x143, 0xc>(v);   // row_bcast:31 -> rows 2,3
    return __int_as_float(__builtin_amdgcn_readlane(__float_as_int(v), 63));
}
template<int CTRL, int RMASK>
__device__ __forceinline__ int dpp_sum_i32(int c) {
    int t = __builtin_amdgcn_update_dpp(0, c, CTRL, RMASK, 0xf, true);  // OOB -> 0
    return c + t;
}
__device__ __forceinline__ int wave_sum_i32(int c) {
    c = dpp_sum_i32<0x111, 0xf>(c);
    c = dpp_sum_i32<0x112, 0xf>(c);
    c = dpp_sum_i32<0x114, 0xf>(c);
    c = dpp_sum_i32<0x118, 0xf>(c);
    c = dpp_sum_i32<0x142, 0xa>(c);
    c = dpp_sum_i32<0x143, 0xc>(c);
    return __builtin_amdgcn_readlane(c, 63);
}
template<int CTRL, int RMASK>
__device__ __forceinline__ int dpp_min_i32(int v) {
    int t = __builtin_amdgcn_update_dpp(v, v, CTRL, RMASK, 0xf, false);
    return min(v, t);
}
__device__ __forceinline__ int wave_min_i32(int v) {
    v = dpp_min_i32<0x111, 0xf>(v);
    v = dpp_min_i32<0x112, 0xf>(v);
    v = dpp_min_i32<0x114, 0xf>(v);
    v = dpp_min_i32<0x118, 0xf>(v);
    v = dpp_min_i32<0x142, 0xa>(v);
    v = dpp_min_i32<0x143, 0xc>(v);
    return __builtin_amdgcn_readlane(v, 63);
}

// =================== THE single kernel: fps | embed+worker roles ===================
__global__ __launch_bounds__(512, 1) void mega_kernel(
    const float* __restrict__ x,
    const float* __restrict__ w1, const float* __restrict__ w2,
    const float* g1, const float* b1, const float* m1, const float* v1,
    const float* g2, const float* b2, const float* m2, const float* v2,
    const float* __restrict__ lw1, const float* __restrict__ lw2,
    const float* lg1, const float* lb1, const float* lm1, const float* lv1,
    const float* lg2, const float* lb2, const float* lm2, const float* lv2,
    float* __restrict__ f, float4* __restrict__ pts4, int* fpsI, int* done,
    float* __restrict__ out0, float* __restrict__ out1,
    float* __restrict__ out2, float* __restrict__ out3)
{
    __shared__ __attribute__((aligned(16))) char smemRaw[131200];
    int tid = threadIdx.x;

    if (blockIdx.x < 8) {
        // ================= FPS role =================
#pragma clang fp contract(off)
        float4* xyzL = (float4*)smemRaw;                 // 128 KB
        u64*    redK = (u64*)(smemRaw + 131072);         // [2][8]
        int b = blockIdx.x;
        int wid = tid >> 6, lane = tid & 63;
        const float* xb = x + (size_t)b * Nx * 3;
        f32x2 px[8], py[8], pz[8], dist[8];    // 16 pts/thread: pair i = pts (16t+2i, 16t+2i+1)
        {
            const float4* xv = (const float4*)(xb + tid * 48);
            float F[48];
#pragma unroll
            for (int q = 0; q < 12; q++) {
                float4 v = xv[q];
                F[q*4+0]=v.x; F[q*4+1]=v.y; F[q*4+2]=v.z; F[q*4+3]=v.w;
            }
#pragma unroll
            for (int i = 0; i < 8; i++) {
                px[i] = (f32x2){F[(2*i)*3+0], F[(2*i+1)*3+0]};
                py[i] = (f32x2){F[(2*i)*3+1], F[(2*i+1)*3+1]};
                pz[i] = (f32x2){F[(2*i)*3+2], F[(2*i+1)*3+2]};
                dist[i] = (f32x2){1e10f, 1e10f};
            }
#pragma unroll
            for (int j = 0; j < 16; j++) {
                int jj = (j + (tid & 15)) & 15;
                xyzL[tid*16 + jj] = make_float4(F[jj*3], F[jj*3+1], F[jj*3+2], 0.f);
            }
        }
        __syncthreads();
        int far = 0;
        for (int st = 0; st < NP; st++) {
            float4 c = xyzL[far];
            if (tid == 0) {
                __hip_atomic_store(&fpsI[b*NP + st], far, __ATOMIC_RELAXED, __HIP_MEMORY_SCOPE_AGENT);
                int o = (b*NP + st) * 3;
                out0[o]=c.x; out0[o+1]=c.y; out0[o+2]=c.z;
                out2[o]=c.x; out2[o+1]=c.y; out2[o+2]=c.z;
            }
            f32x2 cx = {c.x, c.x}, cy = {c.y, c.y}, cz = {c.z, c.z};
            f32x2 bv2 = {-1.0f, -1.0f};
#pragma unroll
            for (int i = 0; i < 8; i++) {
                f32x2 dx = px[i] - cx, dy = py[i] - cy, dz = pz[i] - cz;
                f32x2 sq = (dx*dx + dy*dy) + dz*dz;    // per-lane IEEE, exact np order
                f32x2 dm = __builtin_elementwise_min(dist[i], sq);
                dist[i] = dm;
                bv2 = __builtin_elementwise_max(bv2, dm);
            }
            float bv = fmaxf(bv2.x, bv2.y);
            // per-lane argmax vs OWN bv (independent of the DPP chain -> overlaps it)
            int bi = tid*16;
#pragma unroll
            for (int i = 7; i >= 0; i--) {          // high->low so lowest idx wins
                if (dist[i].y == bv) bi = tid*16 + 2*i + 1;
                if (dist[i].x == bv) bi = tid*16 + 2*i;
            }
            // wave winner: f32 value reduce, then ballot picks lowest matching lane
            float wv = wave_max_f32(bv);
            u64 mask = __ballot(bv == wv);
            int first = (int)__builtin_ctzll(mask);   // lane order == point-index order
            int wbi = __builtin_amdgcn_readlane(bi, first);
            if (lane == 0)
                redK[(st & 1)*8 + wid] = ((u64)__float_as_uint(wv) << 32) | (uint32)(~wbi);
            __syncthreads();
            // lane-parallel cross-wave combine: 1 ds_read_b64 + 3-level u64 DPP
            u64 k8 = redK[(st & 1)*8 + (lane & 7)];
            k8 = dpp_max_u64<0x111, 0xf>(k8);
            k8 = dpp_max_u64<0x112, 0xf>(k8);
            k8 = dpp_max_u64<0x114, 0xf>(k8);   // lane 7 = max over lanes 0..7
            far = (int)(~(uint32)__builtin_amdgcn_readlane((int)(uint32)k8, 7));
        }
        return;
    }

    // ================= Worker role ====================================================
    int wb = (int)blockIdx.x - 8;

    if (wb < NEMB) {
        // ---- embed a 512-point slice: f + pts4 (LDS overlay, released by sync below) --
        float*  W1L = (float*)smemRaw;                    // 192 f  @0
        float4* W2L = (float4*)(smemRaw + 1024);          // 1024 float4
        float*  s1L = (float*)(smemRaw + 17408);
        float*  m1L = (float*)(smemRaw + 17664);
        float*  b1L = (float*)(smemRaw + 17920);
        float*  s2L = (float*)(smemRaw + 18176);
        float*  m2L = (float*)(smemRaw + 18432);
        float*  b2L = (float*)(smemRaw + 18688);
        if (tid < 192) W1L[tid] = w1[tid];
        for (int i = tid; i < 1024; i += 512) W2L[i] = ((const float4*)w2)[i];
        if (tid < 64) {
            s1L[tid] = g1[tid] * (1.0f / sqrtf(v1[tid] + EPS_BN));
            m1L[tid] = m1[tid];  b1L[tid] = b1[tid];
            s2L[tid] = g2[tid] * (1.0f / sqrtf(v2[tid] + EPS_BN));
            m2L[tid] = m2[tid];  b2L[tid] = b2[tid];
        }
        __syncthreads();
        int n = wb * 512 + tid;                 // 0..65535
        const float* xp = x + (size_t)n * 3;
        float x0 = xp[0], x1 = xp[1], x2 = xp[2];
        {
#pragma clang fp contract(off)
            float nv = (x0 * x0 + x1 * x1) + x2 * x2;   // exact np sum order
            pts4[n] = make_float4(x0, x1, x2, nv);
        }
        float t[64];
#pragma unroll
        for (int e = 0; e < 64; e++) {
            float v = fmaf(x2, W1L[e*3+2], fmaf(x1, W1L[e*3+1], x0 * W1L[e*3]));
            v = (v - m1L[e]) * s1L[e] + b1L[e];
            t[e] = fmaxf(v, 0.0f);
        }
        float acc[64];
#pragma unroll
        for (int o = 0; o < 64; o++) acc[o] = 0.0f;
#pragma unroll
        for (int e4 = 0; e4 < 16; e4++) {
            float a0 = t[e4*4], a1 = t[e4*4+1], a2 = t[e4*4+2], a3 = t[e4*4+3];
#pragma unroll
            for (int o = 0; o < 64; o++) {
                float4 w = W2L[o*16 + e4];
                acc[o] = fmaf(a3, w.w, fmaf(a2, w.z, fmaf(a1, w.y, fmaf(a0, w.x, acc[o]))));
            }
        }
        float4* fo = (float4*)(f + (size_t)n * 64);
#pragma unroll
        for (int q = 0; q < 16; q++) {
            float r0 = fmaxf((acc[q*4+0] - m2L[q*4+0]) * s2L[q*4+0] + b2L[q*4+0], 0.f);
            float r1 = fmaxf((acc[q*4+1] - m2L[q*4+1]) * s2L[q*4+1] + b2L[q*4+1], 0.f);
            float r2 = fmaxf((acc[q*4+2] - m2L[q*4+2]) * s2L[q*4+2] + b2L[q*4+2], 0.f);
            float r3 = fmaxf((acc[q*4+3] - m2L[q*4+3]) * s2L[q*4+3] + b2L[q*4+3], 0.f);
            fo[q] = make_float4(r0, r1, r2, r3);
        }
        __syncthreads();      // LDS free for query phase
        if (tid == 0)
            __hip_atomic_fetch_add(done, 1, __ATOMIC_RELEASE, __HIP_MEMORY_SCOPE_AGENT);
    }

    // ---- query-phase LDS overlay ----
    __bf16* featL = (__bf16*)smemRaw;                 // 8704 B
    __bf16* h1L   = (__bf16*)(smemRaw + 8704);        // 8704 B
    float*  cf    = (float*) (smemRaw + 17408);       // 256 B
    int*    rowL  = (int*)   (smemRaw + 17664);       // 128 B
    int*    redC  = (int*)   (smemRaw + 17792);       // [2][8]
    int*    redM  = (int*)   (smemRaw + 17856);       // [2][8]
    int*    misc  = (int*)   (smemRaw + 17920);       // [0]=cnt [1]=idx

    int wv = tid >> 6, lane = tid & 63;
    int l15 = lane & 15, quad = lane >> 4;
    int nbase = wv * 16;
    const f32x4 vzero = {0.f, 0.f, 0.f, 0.f};

    // per-wave weight fragments / bn params, straight from f32 inputs (no prep kernel)
    bf16x8 bf1[4], bf2[4];
#pragma unroll
    for (int kt = 0; kt < 4; kt++) {
        const float* p1 = lw1 + (size_t)(nbase + l15) * 128 + kt*32 + quad*8;
        const float* p2 = lw2 + (size_t)(nbase + l15) * 128 + kt*32 + quad*8;
        bf16x8 a1, a2;
#pragma unroll
        for (int j = 0; j < 8; j++) { a1[j] = (__bf16)p1[j]; a2[j] = (__bf16)p2[j]; }
        bf1[kt] = a1; bf2[kt] = a2;
    }
    int oc = nbase + l15;
    float sc1 = lg1[oc] * (1.0f / sqrtf(lv1[oc] + EPS_BN));
    float mm1 = lm1[oc], bb1 = lb1[oc];
    float sc2 = lg2[oc] * (1.0f / sqrtf(lv2[oc] + EPS_BN));
    float mm2 = lm2[oc], bb2 = lb2[oc];

    // wait for embed completion (cross-XCD: acquire fence before reading f/pts4)
    if (tid == 0) {
        while (__hip_atomic_load(done, __ATOMIC_RELAXED, __HIP_MEMORY_SCOPE_AGENT) != POISON_I + NEMB)
            __builtin_amdgcn_s_sleep(8);
    }
    __syncthreads();
    __threadfence();

    for (int t = wb; t < 8192; t += NWORK) {
        int b = t & 7, s = t >> 3;          // s-major: workers trail fps monotonically
        int q = (b << 10) | s;
        if (tid == 0) {
            int v;
            while ((v = __hip_atomic_load(&fpsI[q], __ATOMIC_RELAXED, __HIP_MEMORY_SCOPE_AGENT)) < 0)
                __builtin_amdgcn_s_sleep(2);
            misc[1] = v;
            misc[0] = 0;
        }
        __syncthreads();
        int cIdx = misc[1];
        if (tid < 16) {      // center features -> cf (consumed after many barriers)
            float4 v = *(const float4*)(f + ((size_t)b * Nx + cIdx) * 64 + tid * 4);
            cf[tid*4]=v.x; cf[tid*4+1]=v.y; cf[tid*4+2]=v.z; cf[tid*4+3]=v.w;
        }
        // ---- KNN radix-select (512 thr, 16 keys each) ----
        uint32 key[16];
        {
#pragma clang fp contract(off)
            const float4* P = pts4 + (size_t)b * Nx;
            float4 qp = P[cIdx];
#pragma unroll
            for (int i = 0; i < 16; i++) {
                int n = tid + (i << 9);
                float4 p = P[n];
                float dot = (qp.x * p.x + qp.y * p.y) + qp.z * p.z;   // exact ref order
                float d = (qp.w + p.w) - 2.0f * dot;
                uint32 u = __float_as_uint(d);
                key[i] = (u & 0x80000000u) ? ~u : (u | 0x80000000u);
            }
        }
        uint32 prefix = 0; int krem = 32;
        for (int bit = 31; bit >= 0; bit--) {
            uint32 sv = prefix >> bit;
            int cnt = 0;
#pragma unroll
            for (int i = 0; i < 16; i++)
                cnt += ((key[i] >> bit) == sv) ? 1 : 0;
            cnt = wave_sum_i32(cnt);
            if (lane == 0) redC[(bit & 1)*8 + wv] = cnt;
            __syncthreads();
            int total = 0;
#pragma unroll
            for (int j = 0; j < 8; j++) total += redC[(bit & 1)*8 + j];
            if (total < krem) { prefix |= (1u << bit); krem -= total; }
        }
#pragma unroll
        for (int i = 0; i < 16; i++) {
            if (key[i] < prefix) {
                int pos = atomicAdd(&misc[0], 1);
                rowL[pos] = tid + (i << 9);
            }
        }
        __syncthreads();
        int last = -1;
        for (int tt = 0; tt < krem; tt++) {    // krem is block-uniform
            int local = 0x7fffffff;
#pragma unroll
            for (int i = 0; i < 16; i++) {
                int n = tid + (i << 9);
                if (key[i] == prefix && n > last && n < local) local = n;
            }
            local = wave_min_i32(local);
            if (lane == 0) redM[(tt & 1)*8 + wv] = local;
            __syncthreads();
            int g = 0x7fffffff;
#pragma unroll
            for (int j = 0; j < 8; j++) g = min(g, redM[(tt & 1)*8 + j]);
            if (tid == 0) rowL[32 - krem + tt] = g;
            last = g;
        }
        __syncthreads();                        // rowL final
        // ---- build feat = [f_nb - f_c | f_c] in bf16 ----
        {
            int k = tid >> 4, j0 = (tid & 15) * 4;
            int nbr = rowL[k];
            float4 v = *(const float4*)(f + ((size_t)b * Nx + nbr) * 64 + j0);
            float c0 = cf[j0], c1 = cf[j0+1], c2 = cf[j0+2], c3 = cf[j0+3];
            __bf16* dl = featL + k * 136 + j0;
            dl[0]=(__bf16)(v.x-c0); dl[1]=(__bf16)(v.y-c1); dl[2]=(__bf16)(v.z-c2); dl[3]=(__bf16)(v.w-c3);
            __bf16* dr = dl + 64;
            dr[0]=(__bf16)c0; dr[1]=(__bf16)c1; dr[2]=(__bf16)c2; dr[3]=(__bf16)c3;
        }
        __syncthreads();
        // ---- layer 1: (32x128)@(128x16 per wave) ----
        f32x4 acc[2];
        acc[0] = vzero; acc[1] = vzero;
#pragma unroll
        for (int mt = 0; mt < 2; mt++)
#pragma unroll
            for (int kt = 0; kt < 4; kt++) {
                bf16x8 a = *(const bf16x8*)(featL + (mt*16 + l15) * 136 + kt*32 + quad*8);
                acc[mt] = __builtin_amdgcn_mfma_f32_16x16x32_bf16(a, bf1[kt], acc[mt], 0, 0, 0);
            }
#pragma unroll
        for (int mt = 0; mt < 2; mt++)
#pragma unroll
            for (int rj = 0; rj < 4; rj++) {
                float h = fmaxf((acc[mt][rj] - mm1) * sc1 + bb1, 0.0f);
                h1L[(mt*16 + quad*4 + rj) * 136 + oc] = (__bf16)h;
            }
        __syncthreads();
        // ---- layer 2 + k-max ----
        acc[0] = vzero; acc[1] = vzero;
#pragma unroll
        for (int mt = 0; mt < 2; mt++)
#pragma unroll
            for (int kt = 0; kt < 4; kt++) {
                bf16x8 a = *(const bf16x8*)(h1L + (mt*16 + l15) * 136 + kt*32 + quad*8);
                acc[mt] = __builtin_amdgcn_mfma_f32_16x16x32_bf16(a, bf2[kt], acc[mt], 0, 0, 0);
            }
        float vmx = 0.0f;                       // relu => >= 0
#pragma unroll
        for (int mt = 0; mt < 2; mt++)
#pragma unroll
            for (int rj = 0; rj < 4; rj++) {
                float h = fmaxf((acc[mt][rj] - mm2) * sc2 + bb2, 0.0f);
                vmx = fmaxf(vmx, h);
            }
        vmx = fmaxf(vmx, __shfl_xor(vmx, 16));
        vmx = fmaxf(vmx, __shfl_xor(vmx, 32));
        if (quad == 0) {
            size_t off = (size_t)b * (128*1024) + (size_t)oc * 1024 + s;
            out1[off] = vmx;
            out3[off] = vmx;
        }
        __syncthreads();                        // LDS reuse next query
    }
}

extern "C" void kernel_launch(void* const* d_in, const int* in_sizes, int n_in,
                              void* d_out, int out_size, void* d_ws, size_t ws_size,
                              hipStream_t stream)
{
    const float* x    = (const float*)d_in[0];
    const float* c1w  = (const float*)d_in[1];
    const float* c2w  = (const float*)d_in[2];
    const float* l1w  = (const float*)d_in[3];
    const float* l2w  = (const float*)d_in[4];
    const float* bn1g = (const float*)d_in[5];
    const float* bn1b = (const float*)d_in[6];
    const float* bn1m = (const float*)d_in[7];
    const float* bn1v = (const float*)d_in[8];
    const float* bn2g = (const float*)d_in[9];
    const float* bn2b = (const float*)d_in[10];
    const float* bn2m = (const float*)d_in[11];
    const float* bn2v = (const float*)d_in[12];
    const float* lb1g = (const float*)d_in[13];
    const float* lb1b = (const float*)d_in[14];
    const float* lb1m = (const float*)d_in[15];
    const float* lb1v = (const float*)d_in[16];
    const float* lb2g = (const float*)d_in[17];
    const float* lb2b = (const float*)d_in[18];
    const float* lb2m = (const float*)d_in[19];
    const float* lb2v = (const float*)d_in[20];

    float* out = (float*)d_out;
    char* ws = (char*)d_ws;
    float*  f    = (float*)(ws);                 // 8*8192*64 f32   = 16,777,216 B
    float4* pts4 = (float4*)(ws + 16777216);     // 8*8192 float4   =  1,048,576 B
    int*    fpsI = (int*)   (ws + 17825792);     // 8*1024 i32 (poison 0xAA = not-ready)
    int*    done = (int*)   (ws + 17858560);     // poison-base counter

    float* out0 = out;              // new_xyz      (8,1024,3)
    float* out1 = out + 24576;      // feature_0    (8,128,1024)
    float* out2 = out + 1073152;    // new_xyz copy
    float* out3 = out + 1097728;    // feature_0 copy

    mega_kernel<<<256, 512, 0, stream>>>(x, c1w, c2w,
        bn1g, bn1b, bn1m, bn1v, bn2g, bn2b, bn2m, bn2v,
        l1w, l2w, lb1g, lb1b, lb1m, lb1v, lb2g, lb2b, lb2m, lb2v,
        f, pts4, fpsI, done, out0, out1, out2, out3);
}